// Round 13
// baseline (197.045 us; speedup 1.0000x reference)
//
#include <hip/hip_runtime.h>
#include <stdint.h>

typedef unsigned long long u64;
typedef unsigned int u32;
typedef int i32x4 __attribute__((ext_vector_type(4)));
typedef int i32x8 __attribute__((ext_vector_type(8)));
typedef float f32x4 __attribute__((ext_vector_type(4)));
typedef float f32x16 __attribute__((ext_vector_type(16)));

constexpr int Bn = 32;    // batch
constexpr int Cn = 512;   // channels (in == out)
constexpr int Ln = 4096;  // length
constexpr int Wn = 8;

// ============================ helpers ============================
__device__ __forceinline__ void gload_lds16(const void* g, void* l) {
    __builtin_amdgcn_global_load_lds(
        (const __attribute__((address_space(1))) u32*)g,
        (__attribute__((address_space(3))) u32*)l, 16, 0, 0);
}

// ===================== FP4 path: pack x + pack w (merged) =====================
// grid: dim3(64, 33), 256 threads.
//   y < 32 : x-pack block — 64 l x 512 ci of sample b=y; f32x4 loads, direct i32x4 stores.
//   y == 32: w-pack block — 8 co per block (32 lanes per co) + zpad init (x==0).
// fp4 e2m1: +1.0 = 0x2, -1.0 = 0xA, 0 = 0x0.
__global__ __launch_bounds__(256) void pack_all_fp4_kernel(
    const float* __restrict__ x, const float* __restrict__ w,
    char* __restrict__ xs4, u32* __restrict__ wq4,
    float* __restrict__ sw, float* __restrict__ zpad,
    float* __restrict__ partial) {
    const int t = threadIdx.x;
    if (blockIdx.y == 32) {
        if (blockIdx.x == 0 && t < 128) zpad[t] = 0.0f;   // 512 B zeros
        const int g32 = t >> 5, lane32 = t & 31;
        const int co = blockIdx.x * 8 + g32;
        const float* wrow = w + (size_t)co * Cn * 3;
        float asum = 0.0f;
#pragma unroll
        for (int u = 0; u < 6; ++u) {
            const int wi = lane32 * 6 + u;                // 0..191
            const int tap = wi >> 6, widx = wi & 63;
            u32 word = 0;
#pragma unroll
            for (int k = 0; k < 8; ++k) {                 // ci = widx*8 + k
                const float v = wrow[(widx * 8 + k) * 3 + tap];
                asum += fabsf(v);
                word |= ((v > 0.0f) ? 0x2u : 0xAu) << (k * 4);
            }
            wq4[(size_t)tap * Cn * 64 + co * 64 + widx] = word;
        }
        for (int off = 16; off; off >>= 1) asum += __shfl_xor(asum, off, 64);
        if (lane32 == 0) sw[co] = asum * (1.0f / (float)(Cn * 3));
        return;
    }
    // ---- x pack ----
    __shared__ float red[4];
    const int b = blockIdx.y, l0 = blockIdx.x * 64;
    const int lr4 = (t & 15) * 4;                      // base l row (4 rows)
    const int cblk = (t >> 4) * 32;                    // 32 consecutive ci
    const float* xb = x + ((size_t)b * Cn + cblk) * Ln + l0 + lr4;
    float asum = 0.0f;
    u32 wds[4][4] = {};
#pragma unroll
    for (int j = 0; j < 32; ++j) {
        const f32x4 v = __builtin_nontemporal_load(
            reinterpret_cast<const f32x4*>(xb + (size_t)j * Ln));
        asum += fabsf(v[0]) + fabsf(v[1]) + fabsf(v[2]) + fabsf(v[3]);
        const int sh = (j & 7) * 4, wi = j >> 3;
        wds[0][wi] |= ((v[0] > 0.0f) ? 0x2u : 0xAu) << sh;
        wds[1][wi] |= ((v[1] > 0.0f) ? 0x2u : 0xAu) << sh;
        wds[2][wi] |= ((v[2] > 0.0f) ? 0x2u : 0xAu) << sh;
        wds[3][wi] |= ((v[3] > 0.0f) ? 0x2u : 0xAu) << sh;
    }
    for (int off = 32; off; off >>= 1) asum += __shfl_xor(asum, off, 64);
    if ((t & 63) == 0) red[t >> 6] = asum;
    __syncthreads();
    if (t == 0) partial[b * 64 + blockIdx.x] = red[0] + red[1] + red[2] + red[3];
#pragma unroll
    for (int r = 0; r < 4; ++r) {
        const i32x4 o = {(int)wds[r][0], (int)wds[r][1], (int)wds[r][2], (int)wds[r][3]};
        *(i32x4*)(xs4 + ((size_t)b * Ln + l0 + lr4 + r) * 256 + (t >> 4) * 16) = o;
    }
}

// ===================== implicit-GEMM MX-FP4 MFMA conv =====================
// grid: 2048 blocks (XCD-swizzled over co_t(4) x lt(16) x b(32)), 512 threads (8 waves)
// block tile: 128 co x 256 l; wave (wr,wcl) owns 64co x 64l as 2x2 of 32x32. BK=64, 3 taps.
// LDS: 3 bufs x (A [3][128][32B]=12288 + B [258][32B]=8256) = 61632, depth-2 prefetch,
// one barrier per kt, counted per-wave vmcnt. Epilogue: 4 rounds x 16co LDS transpose
// -> f32x4 nontemporal stores.
__global__ __launch_bounds__(512, 4) void xgemm_fp4_kernel(
    const char* __restrict__ xs4, const char* __restrict__ wq4,
    const float* __restrict__ sw, const float* __restrict__ partial,
    const float* __restrict__ zpadf, float* __restrict__ out) {
    __shared__ __align__(16) char lds[61632];
    const int tid = threadIdx.x;
    const int lane = tid & 63, wid = tid >> 6;
    const int wr = wid >> 2, wcl = wid & 3;   // wave co-strip / l-strip
    const int cl = lane & 31, kh = lane >> 5; // MFMA col lane, k-half

    // bijective XCD-aware decode: within an XCD, co_t iterates fastest (shares B tile)
    const int X = blockIdx.x;
    const int xcd = X & 7, j = X >> 3;
    const int co_t = j & 3;
    const int P = (j >> 2) * 8 + xcd;         // [0,512)
    const int lt = P & 15, b = P >> 4;
    const int c0 = co_t * 128, l0 = lt * 256;

    // per-sample scale from pack partials (shfl chain drains the load before staging)
    float psum = partial[b * 64 + lane];
    for (int off = 32; off; off >>= 1) psum += __shfl_xor(psum, off, 64);
    const float sxb = psum * (1.0f / (float)((size_t)Cn * Ln));
    asm volatile("" ::: "memory");

    const char* zpad = (const char*)zpadf;

    // staging sources (ko = kt*32 bytes). A slots 0..767: tap=s>>8, r=(s>>1)&127, h=s&1.
    const char* sA0;  // slot tid
    const char* sA1;  // slot 512+(tid&255), waves 0-3
    {
        int s = tid;
        sA0 = wq4 + (size_t)(s >> 8) * Cn * 256 + (size_t)(c0 + ((s >> 1) & 127)) * 256 + (s & 1) * 16;
        s = 512 + (tid & 255);
        sA1 = wq4 + (size_t)(s >> 8) * Cn * 256 + (size_t)(c0 + ((s >> 1) & 127)) * 256 + (s & 1) * 16;
    }
    // B slots 0..515: row=s>>1 (l = l0-1+row), h=s&1
    const char* sB0;
    const char* sB2;
    {
        int s = tid;
        int row = s >> 1, l = l0 - 1 + row;
        sB0 = (l >= 0 && l < Ln) ? xs4 + ((size_t)b * Ln + l) * 256 + (s & 1) * 16 : zpad;
        s = 512 + (lane & 3); row = s >> 1; l = l0 - 1 + row;
        sB2 = (l >= 0 && l < Ln) ? xs4 + ((size_t)b * Ln + l) * 256 + (s & 1) * 16 : zpad;
    }

    // fragment LDS offsets: A row = wr*64+m*32+cl, B row = wcl*64+n*32+cl+tap (stride 32B)
    int aoff[2];
#pragma unroll
    for (int m = 0; m < 2; ++m) aoff[m] = (wr * 64 + m * 32 + cl) * 32 + kh * 16;
    int boff[2][3];
#pragma unroll
    for (int n = 0; n < 2; ++n)
#pragma unroll
        for (int tap = 0; tap < 3; ++tap)
            boff[n][tap] = (wcl * 64 + n * 32 + cl + tap) * 32 + kh * 16;

    f32x16 acc[2][2] = {};

    auto stage = [&](int kt, int tb) {
        char* base = (char*)lds + tb * 20544;
        const int ko = kt * 32;
        gload_lds16(sA0 + ko, base + tid * 16);
        if (wid < 4) gload_lds16(sA1 + ko, base + (512 + (tid & 255)) * 16);
        char* bb = base + 12288;
        gload_lds16(sB0 + ko, bb + tid * 16);
        if (wid == 0) {
            if (lane < 4) gload_lds16(sB2 + ko, bb + (512 + lane) * 16);
        }
    };
    // per-wave loads per stage: w0=4, w1-3=3, w4-7=2

    auto compute = [&](int tb) {
        const char* A = (const char*)lds + tb * 20544;
        const char* Bt = A + 12288;
#pragma unroll
        for (int tap = 0; tap < 3; ++tap) {
            i32x8 av[2], bv[2];
#pragma unroll
            for (int m = 0; m < 2; ++m) {
                const i32x4 t4 = *(const i32x4*)(A + tap * 4096 + aoff[m]);
                av[m] = i32x8{t4[0], t4[1], t4[2], t4[3], 0, 0, 0, 0};
            }
#pragma unroll
            for (int n = 0; n < 2; ++n) {
                const i32x4 t4 = *(const i32x4*)(Bt + boff[n][tap]);
                bv[n] = i32x8{t4[0], t4[1], t4[2], t4[3], 0, 0, 0, 0};
            }
            __builtin_amdgcn_s_setprio(1);
#pragma unroll
            for (int m = 0; m < 2; ++m)
#pragma unroll
                for (int n = 0; n < 2; ++n)
                    acc[m][n] = __builtin_amdgcn_mfma_scale_f32_32x32x64_f8f6f4(
                        av[m], bv[n], acc[m][n], 4 /*fp4 A*/, 4 /*fp4 B*/,
                        0, 0x7F7F7F7F, 0, 0x7F7F7F7F);   // e8m0 scales = 1.0
            __builtin_amdgcn_s_setprio(0);
        }
    };

    // depth-2 prefetch over 3 LDS buffers, one barrier per kt
    stage(0, 0);
    stage(1, 1);
#pragma unroll
    for (int kt = 0; kt < 8; ++kt) {
        const int buf = kt % 3;
        if (kt < 7) {
            if (wid == 0)      asm volatile("s_waitcnt vmcnt(4)" ::: "memory");
            else if (wid < 4)  asm volatile("s_waitcnt vmcnt(3)" ::: "memory");
            else               asm volatile("s_waitcnt vmcnt(2)" ::: "memory");
        } else {
            asm volatile("s_waitcnt vmcnt(0)" ::: "memory");
        }
        __builtin_amdgcn_s_barrier();         // all waves' kt loads landed
        if (kt < 6) stage(kt + 2, (kt + 2) % 3);
        asm volatile("" ::: "memory");
        compute(buf);
        asm volatile("" ::: "memory");
    }

    // ===== epilogue: 4 rounds x 16co LDS transpose -> f32x4 nontemporal stores =====
    // D frag: co = c0 + wr*64 + m*32 + g*8 + kh*4 + q ; l = l0 + wcl*64 + n*32 + cl.
    __syncthreads();                          // K-loop LDS fully retired
    float* ep = (float*)(lds + wid * 4352);   // 8 x 4352B = 34816 <= 61632
#pragma unroll
    for (int rr = 0; rr < 4; ++rr) {
        const int m = rr >> 1, gh = rr & 1;
#pragma unroll
        for (int n = 0; n < 2; ++n)
#pragma unroll
            for (int g2 = 0; g2 < 2; ++g2)
#pragma unroll
                for (int q = 0; q < 4; ++q)
                    ep[(g2 * 8 + kh * 4 + q) * 68 + n * 32 + cl] = acc[m][n][(gh * 2 + g2) * 4 + q];
        __syncthreads();                      // write phase done
#pragma unroll
        for (int ss = 0; ss < 4; ++ss) {
            const int s = ss * 64 + lane;
            const int col = s >> 4, chunk = s & 15;
            f32x4 v = *(f32x4*)&ep[col * 68 + chunk * 4];
            const int co = c0 + wr * 64 + m * 32 + gh * 16 + col;
            v *= (sxb * sw[co]);
            __builtin_nontemporal_store(
                v, (f32x4*)(out + ((size_t)b * Cn + co) * Ln + l0 + wcl * 64 + chunk * 4));
        }
        __syncthreads();                      // before next round overwrites
    }
}

// ===================== fallback popcount path (round-1, passing) =====================
__global__ __launch_bounds__(64) void pack_w_kernel(const float* __restrict__ w,
                                                    u64* __restrict__ wp,
                                                    float* __restrict__ sw) {
    const int co = blockIdx.x;
    const int lane = threadIdx.x;
    const float* wrow = w + (size_t)co * Cn * 3;
    float asum = 0.0f;
    for (int wi = 0; wi < Wn; ++wi) {
        const int ci = wi * 64 + lane;
#pragma unroll
        for (int k = 0; k < 3; ++k) {
            const float v = wrow[ci * 3 + k];
            asum += fabsf(v);
            const u64 m = __ballot(v > 0.0f);
            if (lane == 0) wp[(co * 3 + k) * Wn + wi] = m;
        }
    }
    for (int off = 32; off; off >>= 1) asum += __shfl_xor(asum, off, 64);
    if (lane == 0) sw[co] = asum * (1.0f / (float)(Cn * 3));
}

__global__ __launch_bounds__(256) void pack_x_kernel(const float* __restrict__ x,
                                                     u64* __restrict__ xp,
                                                     float* __restrict__ partial) {
    const int b = blockIdx.z, wi = blockIdx.y;
    const int l = blockIdx.x * 256 + threadIdx.x;
    const float* xb = x + ((size_t)b * Cn + wi * 64) * Ln + l;
    u64 word = 0;
    float asum = 0.0f;
#pragma unroll 8
    for (int c = 0; c < 64; ++c) {
        const float v = xb[(size_t)c * Ln];
        asum += fabsf(v);
        word |= (u64)(v > 0.0f) << c;
    }
    xp[((size_t)b * Wn + wi) * Ln + l] = word;
    for (int off = 32; off; off >>= 1) asum += __shfl_xor(asum, off, 64);
    __shared__ float red[4];
    const int wave = threadIdx.x >> 6, lane = threadIdx.x & 63;
    if (lane == 0) red[wave] = asum;
    __syncthreads();
    if (threadIdx.x == 0)
        partial[b * 128 + wi * 16 + blockIdx.x] = red[0] + red[1] + red[2] + red[3];
}

__global__ __launch_bounds__(128) void finalize_sx_kernel(const float* __restrict__ partial,
                                                          float* __restrict__ sx) {
    const int b = blockIdx.x;
    float v = partial[b * 128 + threadIdx.x];
    for (int off = 32; off; off >>= 1) v += __shfl_xor(v, off, 64);
    __shared__ float red[2];
    if ((threadIdx.x & 63) == 0) red[threadIdx.x >> 6] = v;
    __syncthreads();
    if (threadIdx.x == 0) sx[b] = (red[0] + red[1]) * (1.0f / (float)((size_t)Cn * Ln));
}

__global__ __launch_bounds__(256) void conv_kernel(const u64* __restrict__ xp,
                                                   const u64* __restrict__ wp,
                                                   const float* __restrict__ sw,
                                                   const float* __restrict__ sx,
                                                   float* __restrict__ out) {
    __shared__ u64 wq[64 * 24];
    __shared__ float sws[64];
    const int b = blockIdx.z;
    const int c0 = blockIdx.y * 64;
    const int l0 = blockIdx.x * 64;
    for (int i = threadIdx.x; i < 64 * 24; i += 256) wq[i] = wp[(size_t)c0 * 24 + i];
    if (threadIdx.x < 64) sws[threadIdx.x] = sw[c0 + threadIdx.x];
    __syncthreads();
    const int lane = threadIdx.x & 63;
    const int wv = threadIdx.x >> 6;
    const int l = l0 + lane;
    const bool v0 = (l >= 1);
    const bool v2 = (l < Ln - 1);
    const int lmi = v0 ? l - 1 : l;
    const int lp = v2 ? l + 1 : l;
    const u64* xpb = xp + (size_t)b * Wn * Ln;
    u64 xq0[8], xq1[8], xq2[8];
#pragma unroll
    for (int wi = 0; wi < 8; ++wi) {
        const u64* p = xpb + (size_t)wi * Ln;
        xq0[wi] = p[lmi]; xq1[wi] = p[l]; xq2[wi] = p[lp];
    }
    const float sxb = sx[b];
    const size_t obase = ((size_t)b * Cn + c0 + wv * 16) * Ln + l;
#pragma unroll 2
    for (int ci = 0; ci < 16; ++ci) {
        const int col = wv * 16 + ci;
        const u64* wr = &wq[col * 24];
        int n0 = 0, n1 = 0, n2 = 0;
#pragma unroll
        for (int wi = 0; wi < 8; ++wi) {
            n0 += __popcll(xq0[wi] ^ wr[0 * 8 + wi]);
            n1 += __popcll(xq1[wi] ^ wr[1 * 8 + wi]);
            n2 += __popcll(xq2[wi] ^ wr[2 * 8 + wi]);
        }
        int s = 512 - 2 * n1;
        s += v0 ? (512 - 2 * n0) : 0;
        s += v2 ? (512 - 2 * n2) : 0;
        out[obase + (size_t)ci * Ln] = sxb * sws[col] * (float)s;
    }
}

// ============================ launch ============================
extern "C" void kernel_launch(void* const* d_in, const int* in_sizes, int n_in,
                              void* d_out, int out_size, void* d_ws, size_t ws_size,
                              hipStream_t stream) {
    const float* x = (const float*)d_in[0];   // [32, 512, 4096] f32
    const float* w = (const float*)d_in[1];   // [512, 512, 3]  f32
    float* out = (float*)d_out;               // [32, 512, 4096] f32
    char* ws = (char*)d_ws;

    // fp4 path workspace: xs4 33554432 | wq4 393216 | zpad 512 | sw 2048 | (gap) | partial 8192
    const size_t NEED = 33958528;
    if (ws_size >= NEED) {
        char* xs4 = ws;                              // [b][l][ci/2] fp4
        u32* wq4 = (u32*)(ws + 33554432);            // [tap][co][ci/2] fp4
        float* zpad = (float*)(ws + 33947648);       // 512 B zeros
        float* sw = (float*)(ws + 33948160);
        float* partial = (float*)(ws + 33950336);

        pack_all_fp4_kernel<<<dim3(64, 33), dim3(256), 0, stream>>>(
            x, w, xs4, wq4, sw, zpad, partial);
        xgemm_fp4_kernel<<<dim3(2048), dim3(512), 0, stream>>>(
            xs4, (const char*)wq4, sw, partial, zpad, out);
    } else {
        const size_t xp_bytes = (size_t)Bn * Wn * Ln * sizeof(u64);
        const size_t wp_bytes = (size_t)Cn * 3 * Wn * sizeof(u64);
        u64* xp = (u64*)ws;
        u64* wp = (u64*)(ws + xp_bytes);
        float* sw = (float*)(ws + xp_bytes + wp_bytes);
        float* partial = sw + Cn;
        float* sx = partial + Bn * 128;

        pack_w_kernel<<<dim3(Cn), dim3(64), 0, stream>>>(w, wp, sw);
        pack_x_kernel<<<dim3(Ln / 256, Wn, Bn), dim3(256), 0, stream>>>(x, xp, partial);
        finalize_sx_kernel<<<dim3(Bn), dim3(128), 0, stream>>>(partial, sx);
        conv_kernel<<<dim3(Ln / 64, Cn / 64, Bn), dim3(256), 0, stream>>>(xp, wp, sw, sx, out);
    }
}

// Round 14
// 137.161 us; speedup vs baseline: 1.4366x; 1.4366x over previous
//
#include <hip/hip_runtime.h>
#include <stdint.h>

typedef unsigned long long u64;
typedef unsigned int u32;
typedef int i32x4 __attribute__((ext_vector_type(4)));
typedef int i32x8 __attribute__((ext_vector_type(8)));
typedef float f32x4 __attribute__((ext_vector_type(4)));
typedef float f32x16 __attribute__((ext_vector_type(16)));

constexpr int Bn = 32;    // batch
constexpr int Cn = 512;   // channels (in == out)
constexpr int Ln = 4096;  // length
constexpr int Wn = 8;

// ============================ helpers ============================
__device__ __forceinline__ void gload_lds16(const void* g, void* l) {
    __builtin_amdgcn_global_load_lds(
        (const __attribute__((address_space(1))) u32*)g,
        (__attribute__((address_space(3))) u32*)l, 16, 0, 0);
}

// ===================== FP4 path: pack x + pack w (merged) =====================
// grid: dim3(64, 33), 256 threads.
//   y < 32 : x-pack block — 64 l x 512 ci of sample b=y; f32x4 loads, direct i32x4 stores.
//   y == 32: w-pack block — 8 co per block (32 lanes per co) + zpad init (x==0).
// fp4 e2m1: +1.0 = 0x2, -1.0 = 0xA, 0 = 0x0.
__global__ __launch_bounds__(256) void pack_all_fp4_kernel(
    const float* __restrict__ x, const float* __restrict__ w,
    char* __restrict__ xs4, u32* __restrict__ wq4,
    float* __restrict__ sw, float* __restrict__ zpad,
    float* __restrict__ partial) {
    const int t = threadIdx.x;
    if (blockIdx.y == 32) {
        if (blockIdx.x == 0 && t < 128) zpad[t] = 0.0f;   // 512 B zeros
        const int g32 = t >> 5, lane32 = t & 31;
        const int co = blockIdx.x * 8 + g32;
        const float* wrow = w + (size_t)co * Cn * 3;
        float asum = 0.0f;
#pragma unroll
        for (int u = 0; u < 6; ++u) {
            const int wi = lane32 * 6 + u;                // 0..191
            const int tap = wi >> 6, widx = wi & 63;
            u32 word = 0;
#pragma unroll
            for (int k = 0; k < 8; ++k) {                 // ci = widx*8 + k
                const float v = wrow[(widx * 8 + k) * 3 + tap];
                asum += fabsf(v);
                word |= ((v > 0.0f) ? 0x2u : 0xAu) << (k * 4);
            }
            wq4[(size_t)tap * Cn * 64 + co * 64 + widx] = word;
        }
        for (int off = 16; off; off >>= 1) asum += __shfl_xor(asum, off, 64);
        if (lane32 == 0) sw[co] = asum * (1.0f / (float)(Cn * 3));
        return;
    }
    // ---- x pack ----
    __shared__ float red[4];
    const int b = blockIdx.y, l0 = blockIdx.x * 64;
    const int lr4 = (t & 15) * 4;                      // base l row (4 rows)
    const int cblk = (t >> 4) * 32;                    // 32 consecutive ci
    const float* xb = x + ((size_t)b * Cn + cblk) * Ln + l0 + lr4;
    float asum = 0.0f;
    u32 wds[4][4] = {};
#pragma unroll
    for (int j = 0; j < 32; ++j) {
        const f32x4 v = __builtin_nontemporal_load(
            reinterpret_cast<const f32x4*>(xb + (size_t)j * Ln));
        asum += fabsf(v[0]) + fabsf(v[1]) + fabsf(v[2]) + fabsf(v[3]);
        const int sh = (j & 7) * 4, wi = j >> 3;
        wds[0][wi] |= ((v[0] > 0.0f) ? 0x2u : 0xAu) << sh;
        wds[1][wi] |= ((v[1] > 0.0f) ? 0x2u : 0xAu) << sh;
        wds[2][wi] |= ((v[2] > 0.0f) ? 0x2u : 0xAu) << sh;
        wds[3][wi] |= ((v[3] > 0.0f) ? 0x2u : 0xAu) << sh;
    }
    for (int off = 32; off; off >>= 1) asum += __shfl_xor(asum, off, 64);
    if ((t & 63) == 0) red[t >> 6] = asum;
    __syncthreads();
    if (t == 0) partial[b * 64 + blockIdx.x] = red[0] + red[1] + red[2] + red[3];
#pragma unroll
    for (int r = 0; r < 4; ++r) {
        const i32x4 o = {(int)wds[r][0], (int)wds[r][1], (int)wds[r][2], (int)wds[r][3]};
        *(i32x4*)(xs4 + ((size_t)b * Ln + l0 + lr4 + r) * 256 + (t >> 4) * 16) = o;
    }
}

// ===================== implicit-GEMM MX-FP4 MFMA conv =====================
// grid: 4096 blocks (XCD-swizzled over co_t(8) x lt(16) x b(32)), 256 threads (4 waves)
// block tile: 64 co x 256 l; per-wave 64co x 64l as 2x2 of 32x32, BK=64 ci, 3 taps.
// LDS: 3 bufs x 14400 = 43200 (K-loop), then reused as 4 x 8704B epilogue
// transpose regions (pitch 68 dwords) for f32x4 nontemporal stores.
__global__ __launch_bounds__(256, 3) void xgemm_fp4_kernel(
    const char* __restrict__ xs4, const char* __restrict__ wq4,
    const float* __restrict__ sw, const float* __restrict__ partial,
    const float* __restrict__ zpadf, float* __restrict__ out) {
    __shared__ __align__(16) char lds[43200];
    const int tid = threadIdx.x;
    const int lane = tid & 63, wid = tid >> 6;
    const int wc = wid;                       // wave owns l-strip wid*64
    const int cl = lane & 31, kh = lane >> 5; // MFMA col/row lane, k-half

    // bijective XCD-aware decode: within an XCD, co_t iterates fastest (shares B tile)
    const int X = blockIdx.x;
    const int xcd = X & 7, k = X >> 3;
    const int co_t = k & 7;
    const int P = (k >> 3) * 8 + xcd;         // [0,512)
    const int lt = P & 15, b = P >> 4;
    const int c0 = co_t * 64, l0 = lt * 256;

    // per-sample scale from pack partials (drained BEFORE staging so vmcnt
    // counts in the K-loop stay exact)
    float psum = partial[b * 64 + lane];
    for (int off = 32; off; off >>= 1) psum += __shfl_xor(psum, off, 64);
    const float sxb = psum * (1.0f / (float)((size_t)Cn * Ln));

    const char* zpad = (const char*)zpadf;
    const char* wqb = wq4;

    // staging sources (ko = kt*32 bytes added per K-step); LDS linear.
    const char* sA0;  // slot tid
    const char* sA1;  // slot 256+tid (tid<128), tap 2
    {
        int s = tid;
        sA0 = wqb + (size_t)(s >> 7) * Cn * 256 + (size_t)(c0 + ((s >> 1) & 63)) * 256 + (s & 1) * 16;
        s = 256 + (tid & 127);
        sA1 = wqb + (size_t)(s >> 7) * Cn * 256 + (size_t)(c0 + ((s >> 1) & 63)) * 256 + (s & 1) * 16;
    }
    const char* sB0;
    const char* sB1;
    const char* sB2;
    {
        int s = tid;
        int row = s >> 1, l = l0 - 1 + row;
        sB0 = (l >= 0 && l < Ln) ? xs4 + ((size_t)b * Ln + l) * 256 + (s & 1) * 16 : zpad;
        s = 256 + tid; row = s >> 1; l = l0 - 1 + row;
        sB1 = (l >= 0 && l < Ln) ? xs4 + ((size_t)b * Ln + l) * 256 + (s & 1) * 16 : zpad;
        s = 512 + (lane & 3); row = s >> 1; l = l0 - 1 + row;
        sB2 = (l >= 0 && l < Ln) ? xs4 + ((size_t)b * Ln + l) * 256 + (s & 1) * 16 : zpad;
    }

    // fragment LDS offsets: A row = m*32+cl (co), byte kh*16; B row = wc*64+n*32+cl+tap
    int aoff[2];
#pragma unroll
    for (int m = 0; m < 2; ++m) aoff[m] = (m * 32 + cl) * 32 + kh * 16;
    int boff[2][3];
#pragma unroll
    for (int n = 0; n < 2; ++n)
#pragma unroll
        for (int tap = 0; tap < 3; ++tap)
            boff[n][tap] = (wc * 64 + n * 32 + cl + tap) * 32 + kh * 16;

    f32x16 acc[2][2] = {};

    auto stage = [&](int kt, int tb) {
        char* base = (char*)lds + tb * 14400;
        const int ko = kt * 32;
        gload_lds16(sA0 + ko, base + tid * 16);
        if (wid < 2) gload_lds16(sA1 + ko, base + (256 + tid) * 16);   // tid<128
        char* bb = base + 6144;
        gload_lds16(sB0 + ko, bb + tid * 16);
        gload_lds16(sB1 + ko, bb + (256 + tid) * 16);
        if (wid == 0) {
            if (lane < 4) gload_lds16(sB2 + ko, bb + (512 + lane) * 16);
        }
    };
    // per-wave loads per stage: w0=5, w1=4, w2/3=3

    auto compute = [&](int tb) {
        const char* A = (const char*)lds + tb * 14400;
        const char* Bt = A + 6144;
#pragma unroll
        for (int tap = 0; tap < 3; ++tap) {
            i32x8 av[2], bv[2];
#pragma unroll
            for (int m = 0; m < 2; ++m) {
                const i32x4 t4 = *(const i32x4*)(A + tap * 2048 + aoff[m]);
                av[m] = i32x8{t4[0], t4[1], t4[2], t4[3], 0, 0, 0, 0};
            }
#pragma unroll
            for (int n = 0; n < 2; ++n) {
                const i32x4 t4 = *(const i32x4*)(Bt + boff[n][tap]);
                bv[n] = i32x8{t4[0], t4[1], t4[2], t4[3], 0, 0, 0, 0};
            }
            __builtin_amdgcn_s_setprio(1);
#pragma unroll
            for (int m = 0; m < 2; ++m)
#pragma unroll
                for (int n = 0; n < 2; ++n)
                    acc[m][n] = __builtin_amdgcn_mfma_scale_f32_32x32x64_f8f6f4(
                        av[m], bv[n], acc[m][n], 4 /*fp4 A*/, 4 /*fp4 B*/,
                        0, 0x7F7F7F7F, 0, 0x7F7F7F7F);   // e8m0 scales = 1.0
            __builtin_amdgcn_s_setprio(0);
        }
    };

    // depth-2 prefetch pipeline over 3 LDS buffers, one barrier per kt
    stage(0, 0);
    stage(1, 1);
#pragma unroll
    for (int kt = 0; kt < 8; ++kt) {
        const int buf = kt % 3;
        if (kt < 7) {
            if (wid == 0)      asm volatile("s_waitcnt vmcnt(5)" ::: "memory");
            else if (wid == 1) asm volatile("s_waitcnt vmcnt(4)" ::: "memory");
            else               asm volatile("s_waitcnt vmcnt(3)" ::: "memory");
        } else {
            asm volatile("s_waitcnt vmcnt(0)" ::: "memory");
        }
        __builtin_amdgcn_s_barrier();         // all waves' kt loads landed
        if (kt < 6) stage(kt + 2, (kt + 2) % 3);
        asm volatile("" ::: "memory");
        compute(buf);
        asm volatile("" ::: "memory");
    }

    // ===== epilogue: LDS transpose -> f32x4 nontemporal stores =====
    // D frag: co = c0 + m*32 + g*8 + kh*4 + q ; l = l0 + wc*64 + n*32 + cl.
    __syncthreads();                          // K-loop LDS fully retired
    float* ep = (float*)(lds + wc * 8704);    // 4 x 8704B = 34816 <= 43200
#pragma unroll
    for (int m = 0; m < 2; ++m) {
#pragma unroll
        for (int n = 0; n < 2; ++n)
#pragma unroll
            for (int g = 0; g < 4; ++g)
#pragma unroll
                for (int q = 0; q < 4; ++q)
                    ep[(g * 8 + kh * 4 + q) * 68 + n * 32 + cl] = acc[m][n][g * 4 + q];
        __syncthreads();                      // write phase done (all waves)
#pragma unroll
        for (int s = 0; s < 8; ++s) {
            const int slot = s * 64 + lane;
            const int col = slot >> 4, chunk = slot & 15;   // co_local, l-quad
            f32x4 v = *(f32x4*)&ep[col * 68 + chunk * 4];
            const float sc = sxb * sw[c0 + m * 32 + col];
            v *= sc;
            __builtin_nontemporal_store(
                v, (f32x4*)(out + ((size_t)b * Cn + c0 + m * 32 + col) * Ln
                                + l0 + wc * 64 + chunk * 4));
        }
        __syncthreads();                      // before round m=1 overwrites
    }
}

// ===================== fallback popcount path (round-1, passing) =====================
__global__ __launch_bounds__(64) void pack_w_kernel(const float* __restrict__ w,
                                                    u64* __restrict__ wp,
                                                    float* __restrict__ sw) {
    const int co = blockIdx.x;
    const int lane = threadIdx.x;
    const float* wrow = w + (size_t)co * Cn * 3;
    float asum = 0.0f;
    for (int wi = 0; wi < Wn; ++wi) {
        const int ci = wi * 64 + lane;
#pragma unroll
        for (int k = 0; k < 3; ++k) {
            const float v = wrow[ci * 3 + k];
            asum += fabsf(v);
            const u64 m = __ballot(v > 0.0f);
            if (lane == 0) wp[(co * 3 + k) * Wn + wi] = m;
        }
    }
    for (int off = 32; off; off >>= 1) asum += __shfl_xor(asum, off, 64);
    if (lane == 0) sw[co] = asum * (1.0f / (float)(Cn * 3));
}

__global__ __launch_bounds__(256) void pack_x_kernel(const float* __restrict__ x,
                                                     u64* __restrict__ xp,
                                                     float* __restrict__ partial) {
    const int b = blockIdx.z, wi = blockIdx.y;
    const int l = blockIdx.x * 256 + threadIdx.x;
    const float* xb = x + ((size_t)b * Cn + wi * 64) * Ln + l;
    u64 word = 0;
    float asum = 0.0f;
#pragma unroll 8
    for (int c = 0; c < 64; ++c) {
        const float v = xb[(size_t)c * Ln];
        asum += fabsf(v);
        word |= (u64)(v > 0.0f) << c;
    }
    xp[((size_t)b * Wn + wi) * Ln + l] = word;
    for (int off = 32; off; off >>= 1) asum += __shfl_xor(asum, off, 64);
    __shared__ float red[4];
    const int wave = threadIdx.x >> 6, lane = threadIdx.x & 63;
    if (lane == 0) red[wave] = asum;
    __syncthreads();
    if (threadIdx.x == 0)
        partial[b * 128 + wi * 16 + blockIdx.x] = red[0] + red[1] + red[2] + red[3];
}

__global__ __launch_bounds__(128) void finalize_sx_kernel(const float* __restrict__ partial,
                                                          float* __restrict__ sx) {
    const int b = blockIdx.x;
    float v = partial[b * 128 + threadIdx.x];
    for (int off = 32; off; off >>= 1) v += __shfl_xor(v, off, 64);
    __shared__ float red[2];
    if ((threadIdx.x & 63) == 0) red[threadIdx.x >> 6] = v;
    __syncthreads();
    if (threadIdx.x == 0) sx[b] = (red[0] + red[1]) * (1.0f / (float)((size_t)Cn * Ln));
}

__global__ __launch_bounds__(256) void conv_kernel(const u64* __restrict__ xp,
                                                   const u64* __restrict__ wp,
                                                   const float* __restrict__ sw,
                                                   const float* __restrict__ sx,
                                                   float* __restrict__ out) {
    __shared__ u64 wq[64 * 24];
    __shared__ float sws[64];
    const int b = blockIdx.z;
    const int c0 = blockIdx.y * 64;
    const int l0 = blockIdx.x * 64;
    for (int i = threadIdx.x; i < 64 * 24; i += 256) wq[i] = wp[(size_t)c0 * 24 + i];
    if (threadIdx.x < 64) sws[threadIdx.x] = sw[c0 + threadIdx.x];
    __syncthreads();
    const int lane = threadIdx.x & 63;
    const int wv = threadIdx.x >> 6;
    const int l = l0 + lane;
    const bool v0 = (l >= 1);
    const bool v2 = (l < Ln - 1);
    const int lmi = v0 ? l - 1 : l;
    const int lp = v2 ? l + 1 : l;
    const u64* xpb = xp + (size_t)b * Wn * Ln;
    u64 xq0[8], xq1[8], xq2[8];
#pragma unroll
    for (int wi = 0; wi < 8; ++wi) {
        const u64* p = xpb + (size_t)wi * Ln;
        xq0[wi] = p[lmi]; xq1[wi] = p[l]; xq2[wi] = p[lp];
    }
    const float sxb = sx[b];
    const size_t obase = ((size_t)b * Cn + c0 + wv * 16) * Ln + l;
#pragma unroll 2
    for (int ci = 0; ci < 16; ++ci) {
        const int col = wv * 16 + ci;
        const u64* wr = &wq[col * 24];
        int n0 = 0, n1 = 0, n2 = 0;
#pragma unroll
        for (int wi = 0; wi < 8; ++wi) {
            n0 += __popcll(xq0[wi] ^ wr[0 * 8 + wi]);
            n1 += __popcll(xq1[wi] ^ wr[1 * 8 + wi]);
            n2 += __popcll(xq2[wi] ^ wr[2 * 8 + wi]);
        }
        int s = 512 - 2 * n1;
        s += v0 ? (512 - 2 * n0) : 0;
        s += v2 ? (512 - 2 * n2) : 0;
        out[obase + (size_t)ci * Ln] = sxb * sws[col] * (float)s;
    }
}

// ============================ launch ============================
extern "C" void kernel_launch(void* const* d_in, const int* in_sizes, int n_in,
                              void* d_out, int out_size, void* d_ws, size_t ws_size,
                              hipStream_t stream) {
    const float* x = (const float*)d_in[0];   // [32, 512, 4096] f32
    const float* w = (const float*)d_in[1];   // [512, 512, 3]  f32
    float* out = (float*)d_out;               // [32, 512, 4096] f32
    char* ws = (char*)d_ws;

    // fp4 path workspace: xs4 33554432 | wq4 393216 | zpad 512 | sw 2048 | (gap) | partial 8192
    const size_t NEED = 33958528;
    if (ws_size >= NEED) {
        char* xs4 = ws;                              // [b][l][ci/2] fp4
        u32* wq4 = (u32*)(ws + 33554432);            // [tap][co][ci/2] fp4
        float* zpad = (float*)(ws + 33947648);       // 512 B zeros
        float* sw = (float*)(ws + 33948160);
        float* partial = (float*)(ws + 33950336);

        pack_all_fp4_kernel<<<dim3(64, 33), dim3(256), 0, stream>>>(
            x, w, xs4, wq4, sw, zpad, partial);
        xgemm_fp4_kernel<<<dim3(4096), dim3(256), 0, stream>>>(
            xs4, (const char*)wq4, sw, partial, zpad, out);
    } else {
        const size_t xp_bytes = (size_t)Bn * Wn * Ln * sizeof(u64);
        const size_t wp_bytes = (size_t)Cn * 3 * Wn * sizeof(u64);
        u64* xp = (u64*)ws;
        u64* wp = (u64*)(ws + xp_bytes);
        float* sw = (float*)(ws + xp_bytes + wp_bytes);
        float* partial = sw + Cn;
        float* sx = partial + Bn * 128;

        pack_w_kernel<<<dim3(Cn), dim3(64), 0, stream>>>(w, wp, sw);
        pack_x_kernel<<<dim3(Ln / 256, Wn, Bn), dim3(256), 0, stream>>>(x, xp, partial);
        finalize_sx_kernel<<<dim3(Bn), dim3(128), 0, stream>>>(partial, sx);
        conv_kernel<<<dim3(Ln / 64, Cn / 64, Bn), dim3(256), 0, stream>>>(xp, wp, sw, sx, out);
    }
}